// Round 5
// baseline (1431.462 us; speedup 1.0000x reference)
//
#include <hip/hip_runtime.h>
#include <math.h>

#define N_PAT 16384
#define D_DIM 16384
#define NB    256                 // fused-pass blocks: exactly 1 per CU
#define TPB   1024                // 16 waves
#define ROWS  (N_PAT / NB)        // 64 rows per block
#define VPT   (D_DIM / (TPB * 4)) // 4 float4 per thread
#define NWAVE (TPB / 64)          // 16 waves
#define EPSV  1e-8f

// Load one row of P (64KB) into a register buffer: 4 float4 per thread.
#define LOADROW(buf, rr) do {                                              \
    const float4* __restrict__ pr_ = p0 + (size_t)(rr) * (D_DIM / 4);      \
    _Pragma("unroll")                                                      \
    for (int j_ = 0; j_ < VPT; ++j_) buf[j_] = pr_[TPB * j_];              \
} while (0)

// Per-row: dot/ssq block-reduce using a RAW barrier with lgkmcnt-only drain,
// so the other buffer's prefetch global loads stay in flight across the
// barrier (vmcnt never drained here - HK counted-vmcnt pattern). Then sim +
// online-softmax update of the register-resident partial weighted sum.
#define PROC(buf, slot) do {                                               \
    float dot_ = 0.f, ssq_ = 0.f;                                          \
    _Pragma("unroll")                                                      \
    for (int j_ = 0; j_ < VPT; ++j_) {                                     \
        dot_ = fmaf(buf[j_].x, xv[j_].x, dot_);                            \
        dot_ = fmaf(buf[j_].y, xv[j_].y, dot_);                            \
        dot_ = fmaf(buf[j_].z, xv[j_].z, dot_);                            \
        dot_ = fmaf(buf[j_].w, xv[j_].w, dot_);                            \
        ssq_ = fmaf(buf[j_].x, buf[j_].x, ssq_);                           \
        ssq_ = fmaf(buf[j_].y, buf[j_].y, ssq_);                           \
        ssq_ = fmaf(buf[j_].z, buf[j_].z, ssq_);                           \
        ssq_ = fmaf(buf[j_].w, buf[j_].w, ssq_);                           \
    }                                                                      \
    _Pragma("unroll")                                                      \
    for (int o_ = 32; o_ > 0; o_ >>= 1) {                                  \
        dot_ += __shfl_down(dot_, o_, 64);                                 \
        ssq_ += __shfl_down(ssq_, o_, 64);                                 \
    }                                                                      \
    if (lane == 0) {                                                       \
        volatile float2* rw_ = (volatile float2*)red[slot];                \
        rw_[wid].x = dot_; rw_[wid].y = ssq_;                              \
    }                                                                      \
    asm volatile("s_waitcnt lgkmcnt(0)" ::: "memory");                     \
    __builtin_amdgcn_s_barrier();                                          \
    asm volatile("" ::: "memory");                                         \
    dot_ = 0.f; ssq_ = 0.f;                                                \
    _Pragma("unroll")                                                      \
    for (int w_ = 0; w_ < NWAVE; ++w_) {                                   \
        volatile const float2* rr_ = (volatile const float2*)red[slot];    \
        float2 rv_; rv_.x = rr_[w_].x; rv_.y = rr_[w_].y;                  \
        dot_ += rv_.x; ssq_ += rv_.y;                                      \
    }                                                                      \
    const float s_ = dot_ * inv_xn / fmaxf(sqrtf(ssq_), EPSV);             \
    if (s_ > m) {                                                          \
        const float sc_ = __expf(m - s_);  /* exp(-inf)=0 first row */     \
        l = fmaf(l, sc_, 1.f);                                             \
        _Pragma("unroll")                                                  \
        for (int j_ = 0; j_ < VPT; ++j_) {                                 \
            acc[j_].x = fmaf(acc[j_].x, sc_, buf[j_].x);                   \
            acc[j_].y = fmaf(acc[j_].y, sc_, buf[j_].y);                   \
            acc[j_].z = fmaf(acc[j_].z, sc_, buf[j_].z);                   \
            acc[j_].w = fmaf(acc[j_].w, sc_, buf[j_].w);                   \
        }                                                                  \
        m = s_;                                                            \
    } else {                                                               \
        const float p_ = __expf(s_ - m);                                   \
        l += p_;                                                           \
        _Pragma("unroll")                                                  \
        for (int j_ = 0; j_ < VPT; ++j_) {                                 \
            acc[j_].x = fmaf(p_, buf[j_].x, acc[j_].x);                    \
            acc[j_].y = fmaf(p_, buf[j_].y, acc[j_].y);                    \
            acc[j_].z = fmaf(p_, buf[j_].z, acc[j_].z);                    \
            acc[j_].w = fmaf(p_, buf[j_].w, acc[j_].w);                    \
        }                                                                  \
    }                                                                      \
} while (0)

// Register demand: xv+acc+va+vb = 64 data VGPRs + ~20 temps. Pin exactly
// 4 waves/EU (1 block/CU) -> 128-VGPR budget so nothing spills. (Round-2
// lesson: without the pin the allocator chose 64 VGPRs targeting 2 blocks/CU
// and spilled 5.4 GB of scratch; round-3 lesson: don't let demand approach
// the cap — here it's ~85/128.)
__global__ __launch_bounds__(TPB) __attribute__((amdgpu_waves_per_eu(4, 4)))
void fused_pass_kernel(
    const float* __restrict__ x, const float* __restrict__ P,
    float* __restrict__ accs, float* __restrict__ mlvals)
{
    __shared__ float2 red[2][NWAVE];   // parity slots -> 1 barrier per row
    const int t = threadIdx.x;
    const int b = blockIdx.x;
    const int lane = t & 63;
    const int wid = t >> 6;
    const float4* __restrict__ x4 = (const float4*)x;
    const float4* __restrict__ P4 = (const float4*)P;

    float4 xv[VPT], acc[VPT], va[VPT], vb[VPT];
    float xss = 0.f;
#pragma unroll
    for (int j = 0; j < VPT; ++j) {
        xv[j] = x4[t + TPB * j];
        acc[j] = make_float4(0.f, 0.f, 0.f, 0.f);
        xss += xv[j].x * xv[j].x + xv[j].y * xv[j].y
             + xv[j].z * xv[j].z + xv[j].w * xv[j].w;
    }
#pragma unroll
    for (int o = 32; o > 0; o >>= 1) xss += __shfl_down(xss, o, 64);
    if (lane == 0) red[0][wid] = make_float2(xss, 0.f);
    __syncthreads();
    float xn = 0.f;
#pragma unroll
    for (int w = 0; w < NWAVE; ++w) xn += red[0][w].x;
    const float inv_xn = 1.f / fmaxf(sqrtf(xn), EPSV);
    __syncthreads();

    const float4* __restrict__ p0 = P4 + (size_t)b * ROWS * (D_DIM / 4) + t;

    float m = -INFINITY, l = 0.f;
    LOADROW(va, 0);
    for (int r = 0; r < ROWS; r += 2) {
        LOADROW(vb, r + 1);        // in flight across PROC(va)'s barrier
        PROC(va, 0);
        if (r + 2 < ROWS) LOADROW(va, r + 2);  // in flight across PROC(vb)
        PROC(vb, 1);
    }

    float4* __restrict__ oa = (float4*)(accs + (size_t)b * D_DIM);
#pragma unroll
    for (int j = 0; j < VPT; ++j) oa[t + TPB * j] = acc[j];
    if (t == 0) { mlvals[b] = m; mlvals[NB + b] = l; }
}

// Fused weights + combine: 256 blocks x 256 threads. Each block owns 64
// output d's; its 4 waves split the 256 partials (64 each) for load ILP,
// then LDS tree-reduce. Weights recomputed per block from mlvals (L2-hot).
__global__ __launch_bounds__(256) void combine_kernel(
    const float* __restrict__ accs, const float* __restrict__ mlvals,
    float* __restrict__ out)
{
    __shared__ float wsh[NB];
    __shared__ float red2[4][64];
    __shared__ float mred[4], dred[4];
    const int t = threadIdx.x;
    const int lane = t & 63;
    const int w = t >> 6;

    const float mv = mlvals[t];        // one (m,l) pair per thread
    const float lv = mlvals[NB + t];
    float mm = mv;
#pragma unroll
    for (int o = 32; o > 0; o >>= 1) mm = fmaxf(mm, __shfl_down(mm, o, 64));
    if (lane == 0) mred[w] = mm;
    __syncthreads();
    const float M = fmaxf(fmaxf(mred[0], mred[1]), fmaxf(mred[2], mred[3]));
    const float e = __expf(mv - M);
    float c = lv * e;
#pragma unroll
    for (int o = 32; o > 0; o >>= 1) c += __shfl_down(c, o, 64);
    if (lane == 0) dred[w] = c;
    __syncthreads();
    const float denom = dred[0] + dred[1] + dred[2] + dred[3];
    wsh[t] = e / (denom * (float)N_PAT);
    __syncthreads();

    const int d = blockIdx.x * 64 + lane;
    float s = 0.f;
#pragma unroll 8
    for (int bb = w * (NB / 4); bb < (w + 1) * (NB / 4); ++bb)
        s = fmaf(wsh[bb], accs[(size_t)bb * D_DIM + d], s);
    red2[w][lane] = s;
    __syncthreads();
    if (w == 0)
        out[d] = red2[0][lane] + red2[1][lane] + red2[2][lane] + red2[3][lane];
}

extern "C" void kernel_launch(void* const* d_in, const int* in_sizes, int n_in,
                              void* d_out, int out_size, void* d_ws, size_t ws_size,
                              hipStream_t stream) {
    const float* x = (const float*)d_in[0];        // 128*128 f32
    const float* P = (const float*)d_in[1];        // 16384*16384 f32
    float* out = (float*)d_out;                    // 16384 f32

    float* accs   = (float*)d_ws;                  // NB * D floats = 16 MB
    float* mlvals = accs + (size_t)NB * D_DIM;     // 2*NB floats (m then l)

    fused_pass_kernel<<<NB, TPB, 0, stream>>>(x, P, accs, mlvals);
    combine_kernel<<<D_DIM / 64, 256, 0, stream>>>(accs, mlvals, out);
}

// Round 6
// 211.708 us; speedup vs baseline: 6.7615x; 6.7615x over previous
//
#include <hip/hip_runtime.h>
#include <math.h>

#define N_PAT 16384
#define D_DIM 16384
#define NB    512                 // fused-pass blocks: 2 co-resident per CU (TLP)
#define TPB   1024                // 16 waves
#define ROWS  (N_PAT / NB)        // 32 rows per block
#define VPT   (D_DIM / (TPB * 4)) // 4 float4 per thread
#define NWAVE (TPB / 64)          // 16 waves
#define EPSV  1e-8f

// Fused single pass over P. Round-4 proven body (single v buffer, plain
// __syncthreads, ~63 live VGPRs -> fits the allocator's default 64-VGPR /
// 8-waves-per-EU target WITHOUT spilling; rounds 2/3/5 proved any demand
// above that gets spilled to scratch at 5+ GB). NB=512 -> 2 blocks/CU
// co-resident: block B's loads stream while block A drains its per-row
// reduce barrier (TLP overlap, m114 pattern) — no fragile ILP prefetch.
__global__ __launch_bounds__(TPB) void fused_pass_kernel(
    const float* __restrict__ x, const float* __restrict__ P,
    float* __restrict__ accs, float* __restrict__ mlvals)
{
    __shared__ float2 red[2][NWAVE];   // parity slots -> 1 barrier per row
    const int t = threadIdx.x;
    const int b = blockIdx.x;
    const int lane = t & 63;
    const int wid = t >> 6;
    const float4* __restrict__ x4 = (const float4*)x;
    const float4* __restrict__ P4 = (const float4*)P;

    float4 xv[VPT], acc[VPT], v[VPT];
    float xss = 0.f;
#pragma unroll
    for (int j = 0; j < VPT; ++j) {
        xv[j] = x4[t + TPB * j];
        acc[j] = make_float4(0.f, 0.f, 0.f, 0.f);
        xss += xv[j].x * xv[j].x + xv[j].y * xv[j].y
             + xv[j].z * xv[j].z + xv[j].w * xv[j].w;
    }
#pragma unroll
    for (int o = 32; o > 0; o >>= 1) xss += __shfl_down(xss, o, 64);
    if (lane == 0) red[0][wid] = make_float2(xss, 0.f);
    __syncthreads();
    float xn = 0.f;
#pragma unroll
    for (int w = 0; w < NWAVE; ++w) xn += red[0][w].x;
    const float inv_xn = 1.f / fmaxf(sqrtf(xn), EPSV);
    __syncthreads();

    float m = -INFINITY, l = 0.f;
    for (int r = 0; r < ROWS; ++r) {
        const size_t row = (size_t)b * ROWS + r;
        const float4* __restrict__ pr = P4 + row * (size_t)(D_DIM / 4);
#pragma unroll
        for (int j = 0; j < VPT; ++j) v[j] = pr[t + TPB * j];
        float dot = 0.f, ssq = 0.f;
#pragma unroll
        for (int j = 0; j < VPT; ++j) {
            dot = fmaf(v[j].x, xv[j].x, dot); dot = fmaf(v[j].y, xv[j].y, dot);
            dot = fmaf(v[j].z, xv[j].z, dot); dot = fmaf(v[j].w, xv[j].w, dot);
            ssq = fmaf(v[j].x, v[j].x, ssq);  ssq = fmaf(v[j].y, v[j].y, ssq);
            ssq = fmaf(v[j].z, v[j].z, ssq);  ssq = fmaf(v[j].w, v[j].w, ssq);
        }
#pragma unroll
        for (int o = 32; o > 0; o >>= 1) {
            dot += __shfl_down(dot, o, 64);
            ssq += __shfl_down(ssq, o, 64);
        }
        if (lane == 0) red[r & 1][wid] = make_float2(dot, ssq);
        __syncthreads();
        dot = 0.f; ssq = 0.f;
#pragma unroll
        for (int w = 0; w < NWAVE; ++w) {
            const float2 rv = red[r & 1][w];
            dot += rv.x; ssq += rv.y;
        }
        const float s = dot * inv_xn / fmaxf(sqrtf(ssq), EPSV);
        if (s > m) {                    // block-uniform branch
            const float sc = __expf(m - s);   // exp(-inf)=0 on first row
            l = fmaf(l, sc, 1.f);
#pragma unroll
            for (int j = 0; j < VPT; ++j) {
                acc[j].x = fmaf(acc[j].x, sc, v[j].x);
                acc[j].y = fmaf(acc[j].y, sc, v[j].y);
                acc[j].z = fmaf(acc[j].z, sc, v[j].z);
                acc[j].w = fmaf(acc[j].w, sc, v[j].w);
            }
            m = s;
        } else {
            const float p = __expf(s - m);
            l += p;
#pragma unroll
            for (int j = 0; j < VPT; ++j) {
                acc[j].x = fmaf(p, v[j].x, acc[j].x);
                acc[j].y = fmaf(p, v[j].y, acc[j].y);
                acc[j].z = fmaf(p, v[j].z, acc[j].z);
                acc[j].w = fmaf(p, v[j].w, acc[j].w);
            }
        }
    }

    float4* __restrict__ oa = (float4*)(accs + (size_t)b * D_DIM);
#pragma unroll
    for (int j = 0; j < VPT; ++j) oa[t + TPB * j] = acc[j];
    if (t == 0) { mlvals[b] = m; mlvals[NB + b] = l; }
}

// Fused weights + combine: 256 blocks x 256 threads. Each block owns 64
// output d's; its 4 waves split the 512 partials (128 each) for load ILP,
// then LDS tree-reduce. Weights recomputed per block from mlvals (L2-hot).
__global__ __launch_bounds__(256) void combine_kernel(
    const float* __restrict__ accs, const float* __restrict__ mlvals,
    float* __restrict__ out)
{
    __shared__ float wsh[NB];
    __shared__ float red2[4][64];
    __shared__ float mred[4], dred[4];
    const int t = threadIdx.x;
    const int lane = t & 63;
    const int w = t >> 6;

    // each thread owns 2 of the 512 (m,l) pairs
    const float m0 = mlvals[t],      m1 = mlvals[t + 256];
    const float l0 = mlvals[NB + t], l1 = mlvals[NB + t + 256];
    float mm = fmaxf(m0, m1);
#pragma unroll
    for (int o = 32; o > 0; o >>= 1) mm = fmaxf(mm, __shfl_down(mm, o, 64));
    if (lane == 0) mred[w] = mm;
    __syncthreads();
    const float M = fmaxf(fmaxf(mred[0], mred[1]), fmaxf(mred[2], mred[3]));
    const float e0 = __expf(m0 - M), e1 = __expf(m1 - M);
    float c = l0 * e0 + l1 * e1;
#pragma unroll
    for (int o = 32; o > 0; o >>= 1) c += __shfl_down(c, o, 64);
    if (lane == 0) dred[w] = c;
    __syncthreads();
    const float denom = dred[0] + dred[1] + dred[2] + dred[3];
    const float inv = 1.f / (denom * (float)N_PAT);
    wsh[t] = e0 * inv;
    wsh[t + 256] = e1 * inv;
    __syncthreads();

    const int d = blockIdx.x * 64 + lane;
    float s = 0.f;
#pragma unroll 8
    for (int bb = w * (NB / 4); bb < (w + 1) * (NB / 4); ++bb)
        s = fmaf(wsh[bb], accs[(size_t)bb * D_DIM + d], s);
    red2[w][lane] = s;
    __syncthreads();
    if (w == 0)
        out[d] = red2[0][lane] + red2[1][lane] + red2[2][lane] + red2[3][lane];
}

extern "C" void kernel_launch(void* const* d_in, const int* in_sizes, int n_in,
                              void* d_out, int out_size, void* d_ws, size_t ws_size,
                              hipStream_t stream) {
    const float* x = (const float*)d_in[0];        // 128*128 f32
    const float* P = (const float*)d_in[1];        // 16384*16384 f32
    float* out = (float*)d_out;                    // 16384 f32

    float* accs   = (float*)d_ws;                  // NB * D floats = 32 MB
    float* mlvals = accs + (size_t)NB * D_DIM;     // 2*NB floats (m then l)

    fused_pass_kernel<<<NB, TPB, 0, stream>>>(x, P, accs, mlvals);
    combine_kernel<<<D_DIM / 64, 256, 0, stream>>>(accs, mlvals, out);
}

// Round 7
// 193.217 us; speedup vs baseline: 7.4086x; 1.0957x over previous
//
#include <hip/hip_runtime.h>
#include <math.h>

#define N_PAT 16384
#define D_DIM 16384
#define NB    256                 // fused-pass blocks: exactly 1 per CU
#define TPB   1024                // 16 waves
#define ROWS  (N_PAT / NB)        // 64 rows per block
#define VPT   4                   // float4 per thread (D / (TPB*4))
#define NWAVE 16
#define EPSV  1e-8f

// Key facts driving this shape (rounds 2-6):
//  - allocator pins 1024-thr blocks at 64 VGPR and spills rather than relax
//    -> keep register demand ~46 by homing x and acc in LDS (128.5 KB, fine
//    at 1 block/CU).
//  - cosine sims are in [-1,1] -> softmax needs NO running max: w = exp(s),
//    l += w, acc += w*v. No branch, no rescale, no m state.
//  - prefetch row r+1 BEFORE row r's reduce: __syncthreads' vmcnt(0) drain
//    then waits on loads issued a whole reduce-chain earlier, so HBM streams
//    through the shfl/LDS reduce. Exposed bubble = post-barrier tail only.

// Load one row of P (64KB) into a register buffer: 4 float4 per thread.
#define LOADROW(buf, rr) do {                                              \
    const float4* __restrict__ pr_ =                                      \
        P4 + (size_t)(base_row + (rr)) * (D_DIM / 4) + t;                 \
    _Pragma("unroll")                                                      \
    for (int j_ = 0; j_ < VPT; ++j_) buf[j_] = pr_[1024 * j_];             \
} while (0)

// Per-row: dot/ssq vs x (x read from LDS, address blinded so LICM can't
// hoist it back into 16 registers), wave shfl-reduce, one barrier, broadcast
// red-sum, w = exp(sim), LDS-resident acc RMW.
#define PROC(buf, slot) do {                                               \
    int tx_ = t;                                                           \
    asm volatile("" : "+v"(tx_));   /* blind: keep x reads in LDS */       \
    const float4* __restrict__ xl_ = xsh + tx_;                            \
    float dot_ = 0.f, ssq_ = 0.f;                                          \
    _Pragma("unroll")                                                      \
    for (int j_ = 0; j_ < VPT; ++j_) {                                     \
        const float4 xv_ = xl_[1024 * j_];                                 \
        dot_ = fmaf(buf[j_].x, xv_.x, dot_);                               \
        dot_ = fmaf(buf[j_].y, xv_.y, dot_);                               \
        dot_ = fmaf(buf[j_].z, xv_.z, dot_);                               \
        dot_ = fmaf(buf[j_].w, xv_.w, dot_);                               \
        ssq_ = fmaf(buf[j_].x, buf[j_].x, ssq_);                           \
        ssq_ = fmaf(buf[j_].y, buf[j_].y, ssq_);                           \
        ssq_ = fmaf(buf[j_].z, buf[j_].z, ssq_);                           \
        ssq_ = fmaf(buf[j_].w, buf[j_].w, ssq_);                           \
    }                                                                      \
    _Pragma("unroll")                                                      \
    for (int o_ = 32; o_ > 0; o_ >>= 1) {                                  \
        dot_ += __shfl_down(dot_, o_, 64);                                 \
        ssq_ += __shfl_down(ssq_, o_, 64);                                 \
    }                                                                      \
    if (lane == 0) {                                                       \
        reds[slot][0][wid] = dot_;                                         \
        reds[slot][1][wid] = ssq_;                                         \
    }                                                                      \
    __syncthreads();                /* waits on NEXT row's loads too */    \
    const float4* __restrict__ rp_ = (const float4*)&reds[slot][0][0];     \
    float ds_ = 0.f, ss_ = 0.f;                                            \
    _Pragma("unroll")                                                      \
    for (int w_ = 0; w_ < 4; ++w_) {                                       \
        const float4 a_ = rp_[w_];       /* dots   */                      \
        const float4 b_ = rp_[w_ + 4];   /* ssqs   */                      \
        ds_ += a_.x + a_.y + a_.z + a_.w;                                  \
        ss_ += b_.x + b_.y + b_.z + b_.w;                                  \
    }                                                                      \
    const float w_ = __expf(ds_ * inv_xn / fmaxf(sqrtf(ss_), EPSV));       \
    l += w_;                                                               \
    float4* __restrict__ al_ = accsh + t;                                  \
    _Pragma("unroll")                                                      \
    for (int j_ = 0; j_ < VPT; ++j_) {                                     \
        float4 a_ = al_[1024 * j_];                                        \
        a_.x = fmaf(w_, buf[j_].x, a_.x);                                  \
        a_.y = fmaf(w_, buf[j_].y, a_.y);                                  \
        a_.z = fmaf(w_, buf[j_].z, a_.z);                                  \
        a_.w = fmaf(w_, buf[j_].w, a_.w);                                  \
        al_[1024 * j_] = a_;                                               \
    }                                                                      \
} while (0)

__global__ __launch_bounds__(TPB) void fused_pass_kernel(
    const float* __restrict__ x, const float* __restrict__ P,
    float* __restrict__ accs, float* __restrict__ lvals)
{
    __shared__ float4 xsh[D_DIM / 4];     // 64 KB: x, staged once
    __shared__ float4 accsh[D_DIM / 4];   // 64 KB: block's weighted-sum acc
    __shared__ float reds[2][2][NWAVE];   // [parity][dot|ssq][wave]
    const int t = threadIdx.x;
    const int b = blockIdx.x;
    const int lane = t & 63;
    const int wid = t >> 6;
    const float4* __restrict__ x4 = (const float4*)x;
    const float4* __restrict__ P4 = (const float4*)P;

    // Prologue: stage x into LDS, zero acc, compute ||x||.
    float xss = 0.f;
#pragma unroll
    for (int j = 0; j < VPT; ++j) {
        const float4 xv = x4[t + 1024 * j];
        xsh[t + 1024 * j] = xv;
        accsh[t + 1024 * j] = make_float4(0.f, 0.f, 0.f, 0.f);
        xss += xv.x * xv.x + xv.y * xv.y + xv.z * xv.z + xv.w * xv.w;
    }
#pragma unroll
    for (int o = 32; o > 0; o >>= 1) xss += __shfl_down(xss, o, 64);
    if (lane == 0) reds[0][0][wid] = xss;
    __syncthreads();
    float xn = 0.f;
#pragma unroll
    for (int w = 0; w < NWAVE; ++w) xn += reds[0][0][w];
    const float inv_xn = 1.f / fmaxf(sqrtf(xn), EPSV);
    __syncthreads();                      // reds reused by row 0

    const int base_row = b * ROWS;
    float4 va[VPT], vb[VPT];
    float l = 0.f;

    LOADROW(va, 0);
#pragma unroll 1
    for (int r = 0; r < ROWS; r += 2) {
        LOADROW(vb, r + 1);               // in flight across PROC(va)'s barrier
        PROC(va, 0);
        if (r + 2 < ROWS) LOADROW(va, r + 2);  // in flight across PROC(vb)
        PROC(vb, 1);
    }

    // Epilogue: acc (LDS) -> global partials.
    float4* __restrict__ oa = (float4*)(accs + (size_t)b * D_DIM);
#pragma unroll
    for (int j = 0; j < VPT; ++j) oa[t + 1024 * j] = accsh[t + 1024 * j];
    if (t == 0) lvals[b] = l;
}

// Combine: out[d] = (sum_b acc_b[d]) / (N * sum_b l_b). 256 blocks x 256
// threads; each block owns 64 d's, its 4 waves split the 256 partials,
// LDS tree-reduce. denom recomputed per block from lvals (L2-hot, 1 KB).
__global__ __launch_bounds__(256) void combine_kernel(
    const float* __restrict__ accs, const float* __restrict__ lvals,
    float* __restrict__ out)
{
    __shared__ float dred[4];
    __shared__ float red2[4][64];
    const int t = threadIdx.x;
    const int lane = t & 63;
    const int w = t >> 6;

    float c = lvals[t];                   // 256 threads, 256 values
#pragma unroll
    for (int o = 32; o > 0; o >>= 1) c += __shfl_down(c, o, 64);
    if (lane == 0) dred[w] = c;
    __syncthreads();
    const float denom = dred[0] + dred[1] + dred[2] + dred[3];
    const float inv = 1.f / (denom * (float)N_PAT);

    const int d = blockIdx.x * 64 + lane;
    float s = 0.f;
#pragma unroll 8
    for (int bb = w * (NB / 4); bb < (w + 1) * (NB / 4); ++bb)
        s += accs[(size_t)bb * D_DIM + d];
    red2[w][lane] = s;
    __syncthreads();
    if (w == 0)
        out[d] = (red2[0][lane] + red2[1][lane] + red2[2][lane] + red2[3][lane])
                 * inv;
}

extern "C" void kernel_launch(void* const* d_in, const int* in_sizes, int n_in,
                              void* d_out, int out_size, void* d_ws, size_t ws_size,
                              hipStream_t stream) {
    const float* x = (const float*)d_in[0];        // 128*128 f32
    const float* P = (const float*)d_in[1];        // 16384*16384 f32
    float* out = (float*)d_out;                    // 16384 f32

    float* accs  = (float*)d_ws;                   // NB * D floats = 16 MB
    float* lvals = accs + (size_t)NB * D_DIM;      // NB floats

    fused_pass_kernel<<<NB, TPB, 0, stream>>>(x, P, accs, lvals);
    combine_kernel<<<D_DIM / 64, 256, 0, stream>>>(accs, lvals, out);
}

// Round 8
// 191.825 us; speedup vs baseline: 7.4623x; 1.0073x over previous
//
#include <hip/hip_runtime.h>
#include <math.h>

#define N_PAT 16384
#define D_DIM 16384
#define NB    256                 // fused-pass blocks: exactly 1 per CU
#define TPB   1024                // 16 waves
#define ROWS  (N_PAT / NB)        // 64 rows per block
#define VPT   4                   // float4 per thread (D / (TPB*4))
#define NWAVE 16
#define EPSV  1e-8f

// Shape facts (rounds 2-7):
//  - allocator pins 1024-thr blocks at 64 VGPR and spills rather than relax
//    -> x and acc live in LDS (128.5 KB), register demand ~46.
//  - cosine sims in [-1,1] -> max-free softmax: w = exp(s), l += w.
//  - THIS ROUND: raw s_barrier + lgkmcnt-only drain (T4 counted-vmcnt).
//    __syncthreads()'s mandatory vmcnt(0) drain made HBM idle during the
//    ~300-cy post-barrier tail (red-sum/exp/acc-RMW) = the 193 vs 180 gap.
//    With the raw barrier the compiler auto-inserts a COUNTED vmcnt before
//    each buffer's first use, so the other buffer's loads stream through
//    barrier + tail. Sync correctness of this exact PROC skeleton was
//    validated in rounds 2/5 (absmax 3.7e-9; their failures were spills).

#define LOADROW(buf, rr) do {                                              \
    const float4* __restrict__ pr_ =                                       \
        P4 + (size_t)(base_row + (rr)) * (D_DIM / 4) + t;                  \
    _Pragma("unroll")                                                      \
    for (int j_ = 0; j_ < VPT; ++j_) buf[j_] = pr_[1024 * j_];             \
} while (0)

// Per-row: dot/ssq vs x (x read from LDS, address blinded so LICM can't
// hoist x into 16 registers), wave shfl-reduce, raw barrier (lgkmcnt-only),
// broadcast red-sum, w = exp(sim), LDS-resident acc RMW.
#define PROC(buf, slot) do {                                               \
    int tx_ = t;                                                           \
    asm volatile("" : "+v"(tx_));   /* blind: keep x reads in LDS */       \
    const float4* __restrict__ xl_ = xsh + tx_;                            \
    float dot_ = 0.f, ssq_ = 0.f;                                          \
    _Pragma("unroll")                                                      \
    for (int j_ = 0; j_ < VPT; ++j_) {                                     \
        const float4 xv_ = xl_[1024 * j_];                                 \
        dot_ = fmaf(buf[j_].x, xv_.x, dot_);                               \
        dot_ = fmaf(buf[j_].y, xv_.y, dot_);                               \
        dot_ = fmaf(buf[j_].z, xv_.z, dot_);                               \
        dot_ = fmaf(buf[j_].w, xv_.w, dot_);                               \
        ssq_ = fmaf(buf[j_].x, buf[j_].x, ssq_);                           \
        ssq_ = fmaf(buf[j_].y, buf[j_].y, ssq_);                           \
        ssq_ = fmaf(buf[j_].z, buf[j_].z, ssq_);                           \
        ssq_ = fmaf(buf[j_].w, buf[j_].w, ssq_);                           \
    }                                                                      \
    _Pragma("unroll")                                                      \
    for (int o_ = 32; o_ > 0; o_ >>= 1) {                                  \
        dot_ += __shfl_down(dot_, o_, 64);                                 \
        ssq_ += __shfl_down(ssq_, o_, 64);                                 \
    }                                                                      \
    if (lane == 0) {                                                       \
        reds[slot][0][wid] = dot_;                                         \
        reds[slot][1][wid] = ssq_;                                         \
    }                                                                      \
    asm volatile("s_waitcnt lgkmcnt(0)" ::: "memory");                     \
    __builtin_amdgcn_s_barrier();   /* NO vmcnt drain: prefetch in flight */\
    asm volatile("" ::: "memory");                                         \
    const float4* __restrict__ rp_ = (const float4*)&reds[slot][0][0];     \
    float ds_ = 0.f, ss_ = 0.f;                                            \
    _Pragma("unroll")                                                      \
    for (int w_ = 0; w_ < 4; ++w_) {                                       \
        const float4 a_ = rp_[w_];       /* dots */                        \
        const float4 b_ = rp_[w_ + 4];   /* ssqs */                        \
        ds_ += a_.x + a_.y + a_.z + a_.w;                                  \
        ss_ += b_.x + b_.y + b_.z + b_.w;                                  \
    }                                                                      \
    const float w_ = __expf(ds_ * inv_xn / fmaxf(sqrtf(ss_), EPSV));       \
    l += w_;                                                               \
    float4* __restrict__ al_ = accsh + t;                                  \
    _Pragma("unroll")                                                      \
    for (int j_ = 0; j_ < VPT; ++j_) {                                     \
        float4 a_ = al_[1024 * j_];                                        \
        a_.x = fmaf(w_, buf[j_].x, a_.x);                                  \
        a_.y = fmaf(w_, buf[j_].y, a_.y);                                  \
        a_.z = fmaf(w_, buf[j_].z, a_.z);                                  \
        a_.w = fmaf(w_, buf[j_].w, a_.w);                                  \
        al_[1024 * j_] = a_;                                               \
    }                                                                      \
} while (0)

__global__ __launch_bounds__(TPB) void fused_pass_kernel(
    const float* __restrict__ x, const float* __restrict__ P,
    float* __restrict__ accs, float* __restrict__ lvals)
{
    __shared__ float4 xsh[D_DIM / 4];     // 64 KB: x, staged once
    __shared__ float4 accsh[D_DIM / 4];   // 64 KB: block's weighted-sum acc
    __shared__ float reds[2][2][NWAVE];   // [parity][dot|ssq][wave]
    const int t = threadIdx.x;
    const int b = blockIdx.x;
    const int lane = t & 63;
    const int wid = t >> 6;
    const float4* __restrict__ x4 = (const float4*)x;
    const float4* __restrict__ P4 = (const float4*)P;

    const int base_row = b * ROWS;
    float4 va[VPT], vb[VPT];
    float l = 0.f;

    // Fill the pipeline FIRST so rows 0/1 stream under the x prologue.
    LOADROW(va, 0);
    LOADROW(vb, 1);

    // Prologue: stage x into LDS, zero acc, compute ||x||.
    float xss = 0.f;
#pragma unroll
    for (int j = 0; j < VPT; ++j) {
        const float4 xv = x4[t + 1024 * j];
        xsh[t + 1024 * j] = xv;
        accsh[t + 1024 * j] = make_float4(0.f, 0.f, 0.f, 0.f);
        xss += xv.x * xv.x + xv.y * xv.y + xv.z * xv.z + xv.w * xv.w;
    }
#pragma unroll
    for (int o = 32; o > 0; o >>= 1) xss += __shfl_down(xss, o, 64);
    if (lane == 0) reds[0][0][wid] = xss;
    __syncthreads();
    float xn = 0.f;
#pragma unroll
    for (int w = 0; w < NWAVE; ++w) xn += reds[0][0][w];
    const float inv_xn = 1.f / fmaxf(sqrtf(xn), EPSV);
    __syncthreads();                      // reds reused by row 0

#pragma unroll 1
    for (int r = 0; r < ROWS; r += 2) {
        PROC(va, 0);                      // vb (r+1) streams through this
        if (r + 2 < ROWS) LOADROW(va, r + 2);  // issue as soon as va is dead
        PROC(vb, 1);                      // va (r+2) streams through this
        if (r + 3 < ROWS) LOADROW(vb, r + 3);
    }

    // Epilogue: acc (LDS) -> global partials.
    float4* __restrict__ oa = (float4*)(accs + (size_t)b * D_DIM);
#pragma unroll
    for (int j = 0; j < VPT; ++j) oa[t + 1024 * j] = accsh[t + 1024 * j];
    if (t == 0) lvals[b] = l;
}

// Combine: out[d] = (sum_b acc_b[d]) / (N * sum_b l_b). 256 blocks x 256
// threads; each block owns 64 d's, its 4 waves split the 256 partials,
// LDS tree-reduce. denom recomputed per block from lvals (L2-hot, 1 KB).
__global__ __launch_bounds__(256) void combine_kernel(
    const float* __restrict__ accs, const float* __restrict__ lvals,
    float* __restrict__ out)
{
    __shared__ float dred[4];
    __shared__ float red2[4][64];
    const int t = threadIdx.x;
    const int lane = t & 63;
    const int w = t >> 6;

    float c = lvals[t];                   // 256 threads, 256 values
#pragma unroll
    for (int o = 32; o > 0; o >>= 1) c += __shfl_down(c, o, 64);
    if (lane == 0) dred[w] = c;
    __syncthreads();
    const float denom = dred[0] + dred[1] + dred[2] + dred[3];
    const float inv = 1.f / (denom * (float)N_PAT);

    const int d = blockIdx.x * 64 + lane;
    float s = 0.f;
#pragma unroll 8
    for (int bb = w * (NB / 4); bb < (w + 1) * (NB / 4); ++bb)
        s += accs[(size_t)bb * D_DIM + d];
    red2[w][lane] = s;
    __syncthreads();
    if (w == 0)
        out[d] = (red2[0][lane] + red2[1][lane] + red2[2][lane] + red2[3][lane])
                 * inv;
}

extern "C" void kernel_launch(void* const* d_in, const int* in_sizes, int n_in,
                              void* d_out, int out_size, void* d_ws, size_t ws_size,
                              hipStream_t stream) {
    const float* x = (const float*)d_in[0];        // 128*128 f32
    const float* P = (const float*)d_in[1];        // 16384*16384 f32
    float* out = (float*)d_out;                    // 16384 f32

    float* accs  = (float*)d_ws;                   // NB * D floats = 16 MB
    float* lvals = accs + (size_t)NB * D_DIM;      // NB floats

    fused_pass_kernel<<<NB, TPB, 0, stream>>>(x, P, accs, lvals);
    combine_kernel<<<D_DIM / 64, 256, 0, stream>>>(accs, lvals, out);
}

// Round 9
// 188.135 us; speedup vs baseline: 7.6087x; 1.0196x over previous
//
#include <hip/hip_runtime.h>
#include <hip/hip_bf16.h>
#include <math.h>

#define N_PAT 16384
#define D_DIM 16384
#define NB    256                 // fused-pass blocks: exactly 1 per CU
#define TPB   1024                // 16 waves
#define ROWS  (N_PAT / NB)        // 64 rows per block
#define VPT   4                   // float4 per thread (D / (TPB*4))
#define NWAVE 16
#define EPSV  1e-8f

// Shape facts (rounds 2-8):
//  - allocator pins 1024-thr blocks at 64 VGPR and spills rather than relax
//    -> x and acc live in LDS (128.5 KB), register demand ~46.
//  - cosine sims in [-1,1] -> max-free softmax: w = exp(s), l += w.
//  - raw s_barrier + lgkmcnt-only drain: prefetched row streams through the
//    barrier + tail (counted vmcnt). Proven skeleton, absmax 3.7e-9.
//  - THIS ROUND: partials stored as bf16 (they are pre-normalization sums,
//    scaled by ~3e-9 at the end; bf16 rounding adds ~1e-9 to the output,
//    40x inside threshold). Halves fused WRITE (16->8 MB) and combine
//    FETCH (16->8 MB) — the only remaining non-P traffic.

#define LOADROW(buf, rr) do {                                              \
    const float4* __restrict__ pr_ =                                       \
        P4 + (size_t)(base_row + (rr)) * (D_DIM / 4) + t;                  \
    _Pragma("unroll")                                                      \
    for (int j_ = 0; j_ < VPT; ++j_) buf[j_] = pr_[1024 * j_];             \
} while (0)

#define PROC(buf, slot) do {                                               \
    int tx_ = t;                                                           \
    asm volatile("" : "+v"(tx_));   /* blind: keep x reads in LDS */       \
    const float4* __restrict__ xl_ = xsh + tx_;                            \
    float dot_ = 0.f, ssq_ = 0.f;                                          \
    _Pragma("unroll")                                                      \
    for (int j_ = 0; j_ < VPT; ++j_) {                                     \
        const float4 xv_ = xl_[1024 * j_];                                 \
        dot_ = fmaf(buf[j_].x, xv_.x, dot_);                               \
        dot_ = fmaf(buf[j_].y, xv_.y, dot_);                               \
        dot_ = fmaf(buf[j_].z, xv_.z, dot_);                               \
        dot_ = fmaf(buf[j_].w, xv_.w, dot_);                               \
        ssq_ = fmaf(buf[j_].x, buf[j_].x, ssq_);                           \
        ssq_ = fmaf(buf[j_].y, buf[j_].y, ssq_);                           \
        ssq_ = fmaf(buf[j_].z, buf[j_].z, ssq_);                           \
        ssq_ = fmaf(buf[j_].w, buf[j_].w, ssq_);                           \
    }                                                                      \
    _Pragma("unroll")                                                      \
    for (int o_ = 32; o_ > 0; o_ >>= 1) {                                  \
        dot_ += __shfl_down(dot_, o_, 64);                                 \
        ssq_ += __shfl_down(ssq_, o_, 64);                                 \
    }                                                                      \
    if (lane == 0) {                                                       \
        reds[slot][0][wid] = dot_;                                         \
        reds[slot][1][wid] = ssq_;                                         \
    }                                                                      \
    asm volatile("s_waitcnt lgkmcnt(0)" ::: "memory");                     \
    __builtin_amdgcn_s_barrier();   /* NO vmcnt drain: prefetch in flight */\
    asm volatile("" ::: "memory");                                         \
    const float4* __restrict__ rp_ = (const float4*)&reds[slot][0][0];     \
    float ds_ = 0.f, ss_ = 0.f;                                            \
    _Pragma("unroll")                                                      \
    for (int w_ = 0; w_ < 4; ++w_) {                                       \
        const float4 a_ = rp_[w_];       /* dots */                        \
        const float4 b_ = rp_[w_ + 4];   /* ssqs */                        \
        ds_ += a_.x + a_.y + a_.z + a_.w;                                  \
        ss_ += b_.x + b_.y + b_.z + b_.w;                                  \
    }                                                                      \
    const float w_ = __expf(ds_ * inv_xn / fmaxf(sqrtf(ss_), EPSV));       \
    l += w_;                                                               \
    float4* __restrict__ al_ = accsh + t;                                  \
    _Pragma("unroll")                                                      \
    for (int j_ = 0; j_ < VPT; ++j_) {                                     \
        float4 a_ = al_[1024 * j_];                                        \
        a_.x = fmaf(w_, buf[j_].x, a_.x);                                  \
        a_.y = fmaf(w_, buf[j_].y, a_.y);                                  \
        a_.z = fmaf(w_, buf[j_].z, a_.z);                                  \
        a_.w = fmaf(w_, buf[j_].w, a_.w);                                  \
        al_[1024 * j_] = a_;                                               \
    }                                                                      \
} while (0)

static __device__ __forceinline__ unsigned short f2bf(float f) {
    unsigned int u = __float_as_uint(f);
    // round-to-nearest-even to bf16
    u += 0x7fffu + ((u >> 16) & 1u);
    return (unsigned short)(u >> 16);
}

__global__ __launch_bounds__(TPB) void fused_pass_kernel(
    const float* __restrict__ x, const float* __restrict__ P,
    unsigned short* __restrict__ accs, float* __restrict__ lvals)
{
    __shared__ float4 xsh[D_DIM / 4];     // 64 KB: x, staged once
    __shared__ float4 accsh[D_DIM / 4];   // 64 KB: block's weighted-sum acc
    __shared__ float reds[2][2][NWAVE];   // [parity][dot|ssq][wave]
    const int t = threadIdx.x;
    const int b = blockIdx.x;
    const int lane = t & 63;
    const int wid = t >> 6;
    const float4* __restrict__ x4 = (const float4*)x;
    const float4* __restrict__ P4 = (const float4*)P;

    const int base_row = b * ROWS;
    float4 va[VPT], vb[VPT];
    float l = 0.f;

    // Fill the pipeline FIRST so rows 0/1 stream under the x prologue.
    LOADROW(va, 0);
    LOADROW(vb, 1);

    // Prologue: stage x into LDS, zero acc, compute ||x||.
    float xss = 0.f;
#pragma unroll
    for (int j = 0; j < VPT; ++j) {
        const float4 xv = x4[t + 1024 * j];
        xsh[t + 1024 * j] = xv;
        accsh[t + 1024 * j] = make_float4(0.f, 0.f, 0.f, 0.f);
        xss += xv.x * xv.x + xv.y * xv.y + xv.z * xv.z + xv.w * xv.w;
    }
#pragma unroll
    for (int o = 32; o > 0; o >>= 1) xss += __shfl_down(xss, o, 64);
    if (lane == 0) reds[0][0][wid] = xss;
    __syncthreads();
    float xn = 0.f;
#pragma unroll
    for (int w = 0; w < NWAVE; ++w) xn += reds[0][0][w];
    const float inv_xn = 1.f / fmaxf(sqrtf(xn), EPSV);
    __syncthreads();                      // reds reused by row 0

#pragma unroll 1
    for (int r = 0; r < ROWS; r += 2) {
        PROC(va, 0);                      // vb (r+1) streams through this
        if (r + 2 < ROWS) LOADROW(va, r + 2);  // issue as soon as va is dead
        PROC(vb, 1);                      // va (r+2) streams through this
        if (r + 3 < ROWS) LOADROW(vb, r + 3);
    }

    // Epilogue: acc (LDS, f32) -> global partials (bf16, ushort4 stores).
    ushort4* __restrict__ oa = (ushort4*)(accs + (size_t)b * D_DIM);
#pragma unroll
    for (int j = 0; j < VPT; ++j) {
        const float4 a = accsh[t + 1024 * j];
        ushort4 u;
        u.x = f2bf(a.x); u.y = f2bf(a.y); u.z = f2bf(a.z); u.w = f2bf(a.w);
        oa[t + 1024 * j] = u;
    }
    if (t == 0) lvals[b] = l;
}

// Combine: out[d] = (sum_b acc_b[d]) / (N * sum_b l_b). 64 blocks x 256
// threads; each block owns 256 consecutive d (lane -> 4 d via ushort4
// loads, G13 vectorized bf16), its 4 waves split the 256 partial rows,
// then LDS tree-reduce. denom recomputed per block from lvals (L2-hot).
__global__ __launch_bounds__(256) void combine_kernel(
    const unsigned short* __restrict__ accs, const float* __restrict__ lvals,
    float* __restrict__ out)
{
    __shared__ float dred[4];
    __shared__ float4 red2[4][64];
    const int t = threadIdx.x;
    const int lane = t & 63;
    const int w = t >> 6;

    float c = lvals[t];                   // 256 threads, 256 values
#pragma unroll
    for (int o = 32; o > 0; o >>= 1) c += __shfl_down(c, o, 64);
    if (lane == 0) dred[w] = c;
    __syncthreads();
    const float denom = dred[0] + dred[1] + dred[2] + dred[3];
    const float inv = 1.f / (denom * (float)N_PAT);

    const int d4 = blockIdx.x * 64 + lane;     // ushort4 index of 4 d's
    float4 s = make_float4(0.f, 0.f, 0.f, 0.f);
#pragma unroll 8
    for (int bb = w * (NB / 4); bb < (w + 1) * (NB / 4); ++bb) {
        const ushort4 u =
            ((const ushort4*)(accs + (size_t)bb * D_DIM))[d4];
        s.x += __uint_as_float((unsigned)u.x << 16);
        s.y += __uint_as_float((unsigned)u.y << 16);
        s.z += __uint_as_float((unsigned)u.z << 16);
        s.w += __uint_as_float((unsigned)u.w << 16);
    }
    red2[w][lane] = s;
    __syncthreads();
    if (w == 0) {
        const float4 s0 = red2[0][lane], s1 = red2[1][lane];
        const float4 s2 = red2[2][lane], s3 = red2[3][lane];
        float4 o;
        o.x = (s0.x + s1.x + s2.x + s3.x) * inv;
        o.y = (s0.y + s1.y + s2.y + s3.y) * inv;
        o.z = (s0.z + s1.z + s2.z + s3.z) * inv;
        o.w = (s0.w + s1.w + s2.w + s3.w) * inv;
        ((float4*)out)[d4] = o;
    }
}

extern "C" void kernel_launch(void* const* d_in, const int* in_sizes, int n_in,
                              void* d_out, int out_size, void* d_ws, size_t ws_size,
                              hipStream_t stream) {
    const float* x = (const float*)d_in[0];        // 128*128 f32
    const float* P = (const float*)d_in[1];        // 16384*16384 f32
    float* out = (float*)d_out;                    // 16384 f32

    unsigned short* accs = (unsigned short*)d_ws;  // NB * D bf16 = 8 MB
    float* lvals = (float*)(accs + (size_t)NB * D_DIM);  // NB floats

    fused_pass_kernel<<<NB, TPB, 0, stream>>>(x, P, accs, lvals);
    combine_kernel<<<D_DIM / 256, 256, 0, stream>>>(accs, lvals, out);
}

// Round 10
// 174.526 us; speedup vs baseline: 8.2020x; 1.0780x over previous
//
#include <hip/hip_runtime.h>
#include <hip/hip_bf16.h>
#include <math.h>

#define N_PAT 16384
#define D_DIM 16384
#define NB    256                 // fused-pass blocks: exactly 1 per CU
#define TPB   1024                // 16 waves
#define ROWS  (N_PAT / NB)        // 64 rows per block
#define VPT   4                   // float4 per thread (D / (TPB*4))
#define NWAVE 16
#define EPSV  1e-8f

// Shape facts (rounds 2-9):
//  - allocator pins 1024-thr blocks at 64 VGPR and spills rather than relax
//    -> x and acc live in LDS (128.5 KB), register demand ~46.
//  - cosine sims in [-1,1] -> max-free softmax: w = exp(s), l += w.
//  - raw s_barrier + lgkmcnt-only drain: prefetched row streams through the
//    barrier + tail (counted vmcnt).
//  - bf16 partials (pre-normalization sums; rounding ~1e-9 on output).
//  - THIS ROUND: (1) nontemporal P loads — P is stream-once, nt stops it
//    from thrashing L2/L3 allocation; (2) combine at 256 blocks (4x CUs).

typedef float f32x4 __attribute__((ext_vector_type(4)));

static __device__ __forceinline__ float4 ntload(const float4* p) {
    const f32x4 r = __builtin_nontemporal_load((const f32x4*)p);
    float4 v; v.x = r.x; v.y = r.y; v.z = r.z; v.w = r.w;
    return v;
}

#define LOADROW(buf, rr) do {                                              \
    const float4* __restrict__ pr_ =                                       \
        P4 + (size_t)(base_row + (rr)) * (D_DIM / 4) + t;                  \
    _Pragma("unroll")                                                      \
    for (int j_ = 0; j_ < VPT; ++j_) buf[j_] = ntload(&pr_[1024 * j_]);    \
} while (0)

#define PROC(buf, slot) do {                                               \
    int tx_ = t;                                                           \
    asm volatile("" : "+v"(tx_));   /* blind: keep x reads in LDS */       \
    const float4* __restrict__ xl_ = xsh + tx_;                            \
    float dot_ = 0.f, ssq_ = 0.f;                                          \
    _Pragma("unroll")                                                      \
    for (int j_ = 0; j_ < VPT; ++j_) {                                     \
        const float4 xv_ = xl_[1024 * j_];                                 \
        dot_ = fmaf(buf[j_].x, xv_.x, dot_);                               \
        dot_ = fmaf(buf[j_].y, xv_.y, dot_);                               \
        dot_ = fmaf(buf[j_].z, xv_.z, dot_);                               \
        dot_ = fmaf(buf[j_].w, xv_.w, dot_);                               \
        ssq_ = fmaf(buf[j_].x, buf[j_].x, ssq_);                           \
        ssq_ = fmaf(buf[j_].y, buf[j_].y, ssq_);                           \
        ssq_ = fmaf(buf[j_].z, buf[j_].z, ssq_);                           \
        ssq_ = fmaf(buf[j_].w, buf[j_].w, ssq_);                           \
    }                                                                      \
    _Pragma("unroll")                                                      \
    for (int o_ = 32; o_ > 0; o_ >>= 1) {                                  \
        dot_ += __shfl_down(dot_, o_, 64);                                 \
        ssq_ += __shfl_down(ssq_, o_, 64);                                 \
    }                                                                      \
    if (lane == 0) {                                                       \
        reds[slot][0][wid] = dot_;                                         \
        reds[slot][1][wid] = ssq_;                                         \
    }                                                                      \
    asm volatile("s_waitcnt lgkmcnt(0)" ::: "memory");                     \
    __builtin_amdgcn_s_barrier();   /* NO vmcnt drain: prefetch in flight */\
    asm volatile("" ::: "memory");                                         \
    const float4* __restrict__ rp_ = (const float4*)&reds[slot][0][0];     \
    float ds_ = 0.f, ss_ = 0.f;                                            \
    _Pragma("unroll")                                                      \
    for (int w_ = 0; w_ < 4; ++w_) {                                       \
        const float4 a_ = rp_[w_];       /* dots */                        \
        const float4 b_ = rp_[w_ + 4];   /* ssqs */                        \
        ds_ += a_.x + a_.y + a_.z + a_.w;                                  \
        ss_ += b_.x + b_.y + b_.z + b_.w;                                  \
    }                                                                      \
    const float w_ = __expf(ds_ * inv_xn / fmaxf(sqrtf(ss_), EPSV));       \
    l += w_;                                                               \
    float4* __restrict__ al_ = accsh + t;                                  \
    _Pragma("unroll")                                                      \
    for (int j_ = 0; j_ < VPT; ++j_) {                                     \
        float4 a_ = al_[1024 * j_];                                        \
        a_.x = fmaf(w_, buf[j_].x, a_.x);                                  \
        a_.y = fmaf(w_, buf[j_].y, a_.y);                                  \
        a_.z = fmaf(w_, buf[j_].z, a_.z);                                  \
        a_.w = fmaf(w_, buf[j_].w, a_.w);                                  \
        al_[1024 * j_] = a_;                                               \
    }                                                                      \
} while (0)

static __device__ __forceinline__ unsigned short f2bf(float f) {
    unsigned int u = __float_as_uint(f);
    u += 0x7fffu + ((u >> 16) & 1u);   // round-to-nearest-even
    return (unsigned short)(u >> 16);
}

__global__ __launch_bounds__(TPB) void fused_pass_kernel(
    const float* __restrict__ x, const float* __restrict__ P,
    unsigned short* __restrict__ accs, float* __restrict__ lvals)
{
    __shared__ float4 xsh[D_DIM / 4];     // 64 KB: x, staged once
    __shared__ float4 accsh[D_DIM / 4];   // 64 KB: block's weighted-sum acc
    __shared__ float reds[2][2][NWAVE];   // [parity][dot|ssq][wave]
    const int t = threadIdx.x;
    const int b = blockIdx.x;
    const int lane = t & 63;
    const int wid = t >> 6;
    const float4* __restrict__ x4 = (const float4*)x;
    const float4* __restrict__ P4 = (const float4*)P;

    const int base_row = b * ROWS;
    float4 va[VPT], vb[VPT];
    float l = 0.f;

    // Fill the pipeline FIRST so rows 0/1 stream under the x prologue.
    LOADROW(va, 0);
    LOADROW(vb, 1);

    // Prologue: stage x into LDS, zero acc, compute ||x||.
    float xss = 0.f;
#pragma unroll
    for (int j = 0; j < VPT; ++j) {
        const float4 xv = x4[t + 1024 * j];
        xsh[t + 1024 * j] = xv;
        accsh[t + 1024 * j] = make_float4(0.f, 0.f, 0.f, 0.f);
        xss += xv.x * xv.x + xv.y * xv.y + xv.z * xv.z + xv.w * xv.w;
    }
#pragma unroll
    for (int o = 32; o > 0; o >>= 1) xss += __shfl_down(xss, o, 64);
    if (lane == 0) reds[0][0][wid] = xss;
    __syncthreads();
    float xn = 0.f;
#pragma unroll
    for (int w = 0; w < NWAVE; ++w) xn += reds[0][0][w];
    const float inv_xn = 1.f / fmaxf(sqrtf(xn), EPSV);
    __syncthreads();                      // reds reused by row 0

#pragma unroll 1
    for (int r = 0; r < ROWS; r += 2) {
        PROC(va, 0);                      // vb (r+1) streams through this
        if (r + 2 < ROWS) LOADROW(va, r + 2);  // issue as soon as va is dead
        PROC(vb, 1);                      // va (r+2) streams through this
        if (r + 3 < ROWS) LOADROW(vb, r + 3);
    }

    // Epilogue: acc (LDS, f32) -> global partials (bf16, ushort4 stores).
    ushort4* __restrict__ oa = (ushort4*)(accs + (size_t)b * D_DIM);
#pragma unroll
    for (int j = 0; j < VPT; ++j) {
        const float4 a = accsh[t + 1024 * j];
        ushort4 u;
        u.x = f2bf(a.x); u.y = f2bf(a.y); u.z = f2bf(a.z); u.w = f2bf(a.w);
        oa[t + 1024 * j] = u;
    }
    if (t == 0) lvals[b] = l;
}

// Combine: out[d] = (sum_b acc_b[d]) / (N * sum_b l_b). 256 blocks (4x the
// old 64 -> 4x CU coverage) x 256 threads. Each block owns 16 ushort4
// columns (64 d); thread (g = t>>4, i = t&15) sums 16 rows of column
// blockIdx*16+i, then an LDS tree over the 16 row-groups. accs reads stay
// cached (L2/L3-warm from the fused write; no nt here).
__global__ __launch_bounds__(256) void combine_kernel(
    const unsigned short* __restrict__ accs, const float* __restrict__ lvals,
    float* __restrict__ out)
{
    __shared__ float dred[4];
    __shared__ float4 red2[16][16];
    const int t = threadIdx.x;
    const int lane = t & 63;
    const int w = t >> 6;
    const int g = t >> 4;        // row-group 0..15
    const int i = t & 15;        // column within block
    const int d4 = blockIdx.x * 16 + i;

    float c = lvals[t];                   // 256 threads, 256 values
#pragma unroll
    for (int o = 32; o > 0; o >>= 1) c += __shfl_down(c, o, 64);
    if (lane == 0) dred[w] = c;

    float4 s = make_float4(0.f, 0.f, 0.f, 0.f);
#pragma unroll
    for (int k = 0; k < 16; ++k) {
        const int bb = g * 16 + k;
        const ushort4 u =
            ((const ushort4*)(accs + (size_t)bb * D_DIM))[d4];
        s.x += __uint_as_float((unsigned)u.x << 16);
        s.y += __uint_as_float((unsigned)u.y << 16);
        s.z += __uint_as_float((unsigned)u.z << 16);
        s.w += __uint_as_float((unsigned)u.w << 16);
    }
    red2[g][i] = s;
    __syncthreads();
    const float denom = dred[0] + dred[1] + dred[2] + dred[3];
    const float inv = 1.f / (denom * (float)N_PAT);

    if (g == 0) {                         // threads 0..15 finalize 16 columns
        float4 o = make_float4(0.f, 0.f, 0.f, 0.f);
#pragma unroll
        for (int gg = 0; gg < 16; ++gg) {
            const float4 r = red2[gg][i];
            o.x += r.x; o.y += r.y; o.z += r.z; o.w += r.w;
        }
        o.x *= inv; o.y *= inv; o.z *= inv; o.w *= inv;
        ((float4*)out)[d4] = o;
    }
}

extern "C" void kernel_launch(void* const* d_in, const int* in_sizes, int n_in,
                              void* d_out, int out_size, void* d_ws, size_t ws_size,
                              hipStream_t stream) {
    const float* x = (const float*)d_in[0];        // 128*128 f32
    const float* P = (const float*)d_in[1];        // 16384*16384 f32
    float* out = (float*)d_out;                    // 16384 f32

    unsigned short* accs = (unsigned short*)d_ws;  // NB * D bf16 = 8 MB
    float* lvals = (float*)(accs + (size_t)NB * D_DIM);  // NB floats

    fused_pass_kernel<<<NB, TPB, 0, stream>>>(x, P, accs, lvals);
    combine_kernel<<<D_DIM / 64, 256, 0, stream>>>(accs, lvals, out);
}